// Round 17
// baseline (130.276 us; speedup 1.0000x reference)
//
#include <hip/hip_runtime.h>
#include <math.h>

#define THRESH    0.5f
#define NEG_POSK  3
#define EPSf      1e-6f
#define CCLS      81
#define TILEA     64
#define CHUNKS    16
#define TPB       16      // tiles per block; 384/16 = 24 blocks/batch, all full

__device__ __forceinline__ float iou_xy(float ax0, float ay0, float ax1, float ay1,
                                        float bx0, float by0, float bx1, float by1) {
    float lx = fmaxf(ax0, bx0), ly = fmaxf(ay0, by0);
    float rx = fminf(ax1, bx1), ry = fminf(ay1, by1);
    float w = fmaxf(rx - lx, 0.f), h = fmaxf(ry - ly, 0.f);
    float inter = w * h;
    float aa = (ax1 - ax0) * (ay1 - ay0);
    float ab = (bx1 - bx0) * (by1 - by0);
    return inter / (aa + ab - inter);
}

__device__ __forceinline__ void gload16(const void* g, void* l) {
    __builtin_amdgcn_global_load_lds(
        (const __attribute__((address_space(1))) void*)g,
        (__attribute__((address_space(3))) void*)l, 16, 0, 0);
}

// ---------- kernel 1: per-object best-anchor PARTIAL argmax (16 chunks) ----------
__global__ __launch_bounds__(256) void k_obj_part(const float* __restrict__ boxes,
                                                  const float* __restrict__ dboxes,
                                                  float* __restrict__ part_iou,
                                                  int* __restrict__ part_idx,
                                                  int N, int O) {
    int bo = blockIdx.x;
    int c  = blockIdx.y;
    const float* bb = boxes + (size_t)bo * 4;
    float ax0 = bb[0], ay0 = bb[1], ax1 = bb[2], ay1 = bb[3];
    int chunk = (N + CHUNKS - 1) / CHUNKS;
    int n0 = c * chunk;
    int n1 = min(n0 + chunk, N);
    float best = -1.f; int bi = 0x7FFFFFFF;
    for (int n = n0 + threadIdx.x; n < n1; n += 256) {
        float4 d = ((const float4*)dboxes)[n];
        float dx0 = d.x - d.z * 0.5f, dy0 = d.y - d.w * 0.5f;
        float dx1 = d.x + d.z * 0.5f, dy1 = d.y + d.w * 0.5f;
        float iou = iou_xy(ax0, ay0, ax1, ay1, dx0, dy0, dx1, dy1);
        if (iou > best) { best = iou; bi = n; }   // ascending n + strict > = first max
    }
    #pragma unroll
    for (int dd = 1; dd < 64; dd <<= 1) {
        float v2 = __shfl_xor(best, dd); int i2 = __shfl_xor(bi, dd);
        if (v2 > best || (v2 == best && i2 < bi)) { best = v2; bi = i2; }
    }
    __shared__ float sv[4]; __shared__ int si[4];
    int w = threadIdx.x >> 6;
    if ((threadIdx.x & 63) == 0) { sv[w] = best; si[w] = bi; }
    __syncthreads();
    if (threadIdx.x == 0) {
        #pragma unroll
        for (int i = 1; i < 4; ++i)
            if (sv[i] > best || (sv[i] == best && si[i] < bi)) { best = sv[i]; bi = si[i]; }
        part_iou[(size_t)bo * CHUNKS + c] = best;
        part_idx[(size_t)bo * CHUNKS + c] = bi;
    }
}

// ---------- kernel 2: reduce the 16 partials per (b,o) ---------------------------
__global__ void k_obj_reduce(const float* __restrict__ part_iou,
                             const int* __restrict__ part_idx,
                             int* __restrict__ defbox_object, int BO) {
    int bo = blockIdx.x * blockDim.x + threadIdx.x;
    if (bo >= BO) return;
    float best = -1.f; int bi = 0x7FFFFFFF;
    #pragma unroll
    for (int c = 0; c < CHUNKS; ++c) {
        float v = part_iou[(size_t)bo * CHUNKS + c];
        int  i = part_idx[(size_t)bo * CHUNKS + c];
        if (v > best || (v == best && i < bi)) { best = v; bi = i; }
    }
    defbox_object[bo] = bi;
}

// ---------- kernel 3: per-wave pipelines + REGISTER double-buffered ds_reads -----
// R13 skeleton (4-wave blocks, 3/CU, per-wave counted-vmcnt, no in-loop barriers).
// New: each lane's 21 row floats are ds_read one tile EARLY into registers; the
// match phase (independent of row data) hides the LDS latency; stage(t+2) is
// issued only after lgkmcnt(0) so no LDS read ever races the gload overwrite.
template<int OT>
__global__ __launch_bounds__(256)
void k_conf(const float* __restrict__ locs_pred,
            const float* __restrict__ cls,
            const float* __restrict__ boxes,
            const int* __restrict__ labels,
            const float* __restrict__ dboxes,
            const int* __restrict__ dbo_g,
            float* __restrict__ vneg,
            int* __restrict__ n_pos,
            float* __restrict__ loc_sum,
            float* __restrict__ pos_conf,
            int N, int O_rt, int bpb, int tilesPerBatch, long long maxF4) {
    const int O = OT ? OT : O_rt;
    __shared__ __align__(16) float sm[4][2][16 * CCLS];   // per-wave dbuf, 41.5 KB
    __shared__ float sbb[64];
    __shared__ int slab[16], sdbo[16];
    __shared__ float swl[4], swp[4];
    __shared__ int swc[4];
    const int tid = threadIdx.x;
    const int b  = blockIdx.x / bpb;
    const int t0 = (blockIdx.x % bpb) * TPB;
    const int tEnd = min(t0 + TPB, tilesPerBatch);

    if (tid < O * 4) sbb[tid] = boxes[(size_t)b * O * 4 + tid];
    else if (tid < O * 5) slab[tid - O * 4] = labels[(size_t)b * O + tid - O * 4];
    else if (tid < O * 6) sdbo[tid - O * 5] = dbo_g[(size_t)b * O + tid - O * 5];

    const int lane = tid & 63, w = tid >> 6;
    const int j = lane & 15, q = lane >> 4;

    auto stage = [&](int buf, int t) {
        long long base4 = (((long long)b * N + (long long)t * TILEA + w * 16)
                           * CCLS) >> 2;               // exact (divisible by 4)
        const float4* g4 = (const float4*)cls;
        float4* s4 = (float4*)&sm[w][buf][0];
        #pragma unroll
        for (int k2 = 0; k2 < 5; ++k2) {
            long long gi = base4 + k2 * 64 + lane;
            if (gi > maxF4) gi = maxF4;                // clamp (tail-of-buffer OOB)
            gload16(g4 + gi, s4 + k2 * 64);            // wave-uniform LDS base
        }
        if (lane < 4) {
            long long gi = base4 + 320 + lane;
            if (gi > maxF4) gi = maxF4;
            gload16(g4 + gi, s4 + 320);                // tail 4 float4
        }
    };

    auto loadRegs = [&](float (&RR)[20], float& R80, int bufIdx) {
        const float* rowp = &sm[w][bufIdx][j * CCLS];
        __builtin_amdgcn_sched_barrier(0);
        #pragma unroll
        for (int i = 0; i < 20; ++i) RR[i] = rowp[q * 20 + i];
        R80 = rowp[80];
        __builtin_amdgcn_sched_barrier(0);
    };

    stage(0, t0);
    __syncthreads();                                   // publish sbb + drain stage(t0)

    float obx0[4], oby0[4], obx1[4], oby1[4], oarea[4];
    int odbo[4];
    #pragma unroll
    for (int oo = 0; oo < 4; ++oo) {
        int o = q * 4 + oo;
        obx0[oo] = sbb[o*4];   oby0[oo] = sbb[o*4+1];
        obx1[oo] = sbb[o*4+2]; oby1[oo] = sbb[o*4+3];
        oarea[oo] = (obx1[oo] - obx0[oo]) * (oby1[oo] - oby0[oo]);
        odbo[oo] = sdbo[o];
    }

    float pc = 0.f, ls = 0.f; int cnt = 0;

    struct MRes { float4 d, p; int lbl, sel, n; bool act; };

    auto matchTile = [&](int t) -> MRes {
        MRes m;
        int a0 = t * TILEA;
        int a = w * 16 + j;
        m.n = a0 + a;
        m.act = m.n < N;
        int nc = min(m.n, N - 1);
        size_t idx = (size_t)b * N + nc;
        m.d = ((const float4*)dboxes)[nc];             // VMEM #1
        m.p = make_float4(0.f, 0.f, 0.f, 0.f);
        if (q == 0) m.p = ((const float4*)locs_pred)[idx];   // VMEM #2 (early issue)
        float dx0 = m.d.x - m.d.z * 0.5f, dy0 = m.d.y - m.d.w * 0.5f;
        float dx1 = m.d.x + m.d.z * 0.5f, dy1 = m.d.y + m.d.w * 0.5f;
        float areaD = m.d.z * m.d.w;
        float bi = -1.f, bu = 1.f; int bsel = q * 4;
        int fs = -1;
        #pragma unroll
        for (int oo = 0; oo < 4; ++oo) {
            float lx = fmaxf(obx0[oo], dx0), ly = fmaxf(oby0[oo], dy0);
            float rx = fminf(obx1[oo], dx1), ry = fminf(oby1[oo], dy1);
            float ww = fmaxf(rx - lx, 0.f), hh = fmaxf(ry - ly, 0.f);
            float inter = ww * hh;
            float uni = oarea[oo] + areaD - inter;
            float c1 = inter * bu, c2 = bi * uni;
            if (c1 > c2) { bi = inter; bu = uni; bsel = q * 4 + oo; }  // strict >
            if (odbo[oo] == m.n) fs = q * 4 + oo;      // last-wins within group
        }
        #pragma unroll
        for (int dd = 16; dd < 64; dd <<= 1) {
            float oi = __shfl_xor(bi, dd), ou = __shfl_xor(bu, dd);
            int os = __shfl_xor(bsel, dd);
            int of = __shfl_xor(fs, dd);
            float c1 = oi * bu, c2 = bi * ou;
            if (c1 > c2 || (c1 == c2 && os < bsel)) { bi = oi; bu = ou; bsel = os; }
            fs = max(fs, of);                          // last-wins overall
        }
        bool forced = fs >= 0;
        m.sel = forced ? fs : bsel;
        bool meets = forced || (bi >= 0.5f * bu);      // iou >= 0.5
        m.lbl = meets ? slab[m.sel] : 0;
        return m;
    };

    auto expStore = [&](const float (&RR)[20], float R80, const MRes& m) {
        float e0 = 0.f, e1 = 0.f, e2 = 0.f, e3 = 0.f;
        #pragma unroll
        for (int i = 0; i < 20; i += 4) {
            e0 += __expf(RR[i]);     e1 += __expf(RR[i + 1]);
            e2 += __expf(RR[i + 2]); e3 += __expf(RR[i + 3]);
        }
        float s_ = (e0 + e1) + (e2 + e3);
        if (q == 3) s_ += __expf(R80);
        float xl = (m.lbl == 80 && q == 3) ? R80 : 0.f;
        #pragma unroll
        for (int i = 0; i < 20; ++i)
            if (q * 20 + i == m.lbl) xl = RR[i];       // unrolled reg-select
        s_ += __shfl_xor(s_, 16);
        xl += __shfl_xor(xl, 16);                      // two indep shfl chains
        s_ += __shfl_xor(s_, 32);
        xl += __shfl_xor(xl, 32);
        if (m.act && q == 0) {
            float conf = __logf(s_) - xl;
            bool pos = (m.lbl != 0);
            size_t idx = (size_t)b * N + m.n;
            vneg[idx] = pos ? 0.f : conf;              // VMEM #3
            if (pos) {
                pc += conf; cnt++;
                int sel = m.sel;
                float bx0 = sbb[sel*4], by0 = sbb[sel*4+1];
                float bx1 = sbb[sel*4+2], by1 = sbb[sel*4+3];
                float bcx = (bx0 + bx1) * 0.5f, bcy = (by0 + by1) * 0.5f;
                float bw = bx1 - bx0, bh = by1 - by0;
                float t0f = (bcx - m.d.x) / (m.d.z / 10.0f + EPSf);
                float t1f = (bcy - m.d.y) / (m.d.w / 10.0f + EPSf);
                float t2f = __logf(bw / m.d.z + EPSf) * 5.0f;
                float t3f = __logf(bh / m.d.w + EPSf) * 5.0f;
                float dd2;
                dd2 = fabsf(m.p.x - t0f); ls += (dd2 < 1.f) ? 0.5f*dd2*dd2 : dd2 - 0.5f;
                dd2 = fabsf(m.p.y - t1f); ls += (dd2 < 1.f) ? 0.5f*dd2*dd2 : dd2 - 0.5f;
                dd2 = fabsf(m.p.z - t2f); ls += (dd2 < 1.f) ? 0.5f*dd2*dd2 : dd2 - 0.5f;
                dd2 = fabsf(m.p.w - t3f); ls += (dd2 < 1.f) ? 0.5f*dd2*dd2 : dd2 - 0.5f;
            }
        }
    };

    float rrA[20], r80A, rrB[20], r80B;
    loadRegs(rrA, r80A, 0);                            // tile t0 rows -> regs A
    stage(1, t0 + 1);                                  // 6 VMEM (t0+1)

    int t = t0;
    #pragma unroll 1
    for (int half = 0; half < TPB / 2; ++half) {
        {   // EVEN: compute A(t); load B(t+1); stage(t+2)
            bool hasNext = (t + 1 < tEnd);
            if (hasNext) {
                if (t == t0) asm volatile("s_waitcnt vmcnt(0)" ::: "memory");
                else         asm volatile("s_waitcnt vmcnt(1)" ::: "memory");
                loadRegs(rrB, r80B, (t + 1 - t0) & 1);
            }
            MRes m = matchTile(t);                     // hides ds latency
            asm volatile("s_waitcnt lgkmcnt(0)" ::: "memory");
            if (t + 2 < tEnd) stage((t - t0) & 1, t + 2);
            expStore(rrA, r80A, m);
        }
        ++t; if (t >= tEnd) break;
        {   // ODD: compute B(t); load A(t+1); stage(t+2)
            bool hasNext = (t + 1 < tEnd);
            if (hasNext) {
                asm volatile("s_waitcnt vmcnt(1)" ::: "memory");
                loadRegs(rrA, r80A, (t + 1 - t0) & 1);
            }
            MRes m = matchTile(t);
            asm volatile("s_waitcnt lgkmcnt(0)" ::: "memory");
            if (t + 2 < tEnd) stage((t - t0) & 1, t + 2);
            expStore(rrB, r80B, m);
        }
        ++t; if (t >= tEnd) break;
    }

    #pragma unroll
    for (int dd = 1; dd < 64; dd <<= 1) {
        pc  += __shfl_xor(pc, dd);
        ls  += __shfl_xor(ls, dd);
        cnt += __shfl_xor(cnt, dd);
    }
    if (lane == 0) { swp[w] = pc; swl[w] = ls; swc[w] = cnt; }
    __syncthreads();
    if (tid == 0) {
        float P = swp[0] + swp[1] + swp[2] + swp[3];
        float L = swl[0] + swl[1] + swl[2] + swl[3];
        int   C = swc[0] + swc[1] + swc[2] + swc[3];
        if (C) {
            atomicAdd(&n_pos[b], C);
            atomicAdd(loc_sum, L);
            atomicAdd(pos_conf, P);
        }
    }
}

// ---------- kernel 4: exact top-k sum (plain-LDS-atomic, proven fast) ------------
__device__ void wave_select(const int* hist, int nbins, int k, int* out_bin, int* out_k) {
    int lane = threadIdx.x & 63;
    int cum = 0;
    for (int c = nbins / 64 - 1; c >= 0; --c) {
        int val = hist[c * 64 + lane];
        int s = val;                           // descending suffix-sum within chunk
        for (int d = 1; d < 64; d <<= 1) {
            int t = __shfl_down(s, d);
            if (lane + d < 64) s += t;
        }
        int total = __shfl(s, 0);
        if (cum + total >= k) {
            unsigned long long mask = __ballot(cum + s >= k);
            int bl = 63 - __builtin_clzll(mask);
            int sB = __shfl(s, bl);
            int vB = __shfl(val, bl);
            if (lane == 0) {
                *out_bin = c * 64 + bl;
                *out_k = k - (cum + sB - vB);
            }
            return;
        }
        cum += total;
    }
    if (lane == 0) { *out_bin = 0; *out_k = 1; }
}

__global__ __launch_bounds__(1024) void k_select(const float* __restrict__ vneg,
                                                 const int* __restrict__ n_pos,
                                                 float* __restrict__ hard_sum,
                                                 int B, int N) {
    int b = blockIdx.x;
    const float* v = vneg + (size_t)b * N;
    __shared__ int hist[2048];
    __shared__ int bcast_bin, bcast_k;
    __shared__ float swv[16];
    __shared__ int swc[16];
    int np = n_pos[b];
    long long kk = (long long)NEG_POSK * np;
    if (kk > N) kk = N;
    int k = (int)kk;
    if (k <= 0) return;   // uniform across block
    int tid = threadIdx.x;

    for (int i = tid; i < 2048; i += 1024) hist[i] = 0;
    __syncthreads();
    for (int n = tid; n < N; n += 1024) {
        unsigned u = __float_as_uint(v[n]);
        atomicAdd(&hist[u >> 20], 1);
    }
    __syncthreads();
    if (tid < 64) wave_select(hist, 2048, k, &bcast_bin, &bcast_k);
    __syncthreads();
    int B1 = bcast_bin, k2 = bcast_k;

    for (int i = tid; i < 2048; i += 1024) hist[i] = 0;
    __syncthreads();
    for (int n = tid; n < N; n += 1024) {
        unsigned u = __float_as_uint(v[n]);
        if ((int)(u >> 20) == B1) atomicAdd(&hist[(u >> 9) & 0x7FF], 1);
    }
    __syncthreads();
    if (tid < 64) wave_select(hist, 2048, k2, &bcast_bin, &bcast_k);
    __syncthreads();
    int B2 = bcast_bin, k3 = bcast_k;
    unsigned pre = ((unsigned)B1 << 11) | (unsigned)B2;

    for (int i = tid; i < 512; i += 1024) hist[i] = 0;
    __syncthreads();
    for (int n = tid; n < N; n += 1024) {
        unsigned u = __float_as_uint(v[n]);
        if ((u >> 9) == pre) atomicAdd(&hist[u & 0x1FF], 1);
    }
    __syncthreads();
    if (tid < 64) wave_select(hist, 512, k3, &bcast_bin, &bcast_k);
    __syncthreads();
    unsigned tau_bits = (pre << 9) | (unsigned)bcast_bin;
    float tau = __uint_as_float(tau_bits);

    float ssum = 0.f; int scnt = 0;
    for (int n = tid; n < N; n += 1024) {
        float x = v[n];
        if (x > tau) { ssum += x; scnt++; }
    }
    for (int d = 1; d < 64; d <<= 1) {
        ssum += __shfl_xor(ssum, d);
        scnt += __shfl_xor(scnt, d);
    }
    int w = tid >> 6;
    if ((tid & 63) == 0) { swv[w] = ssum; swc[w] = scnt; }
    __syncthreads();
    if (tid == 0) {
        float S = 0.f; int Ct = 0;
        for (int i = 0; i < 16; ++i) { S += swv[i]; Ct += swc[i]; }
        float hb = S + (float)(k - Ct) * tau;
        atomicAdd(hard_sum, hb);
    }
}

// ---------- kernel 5: finalize ---------------------------------------------------
__global__ void k_final(const int* __restrict__ n_pos,
                        const float* __restrict__ loc_sum,
                        const float* __restrict__ pos_conf,
                        const float* __restrict__ hard_sum,
                        float* __restrict__ out, int B) {
    if (threadIdx.x == 0 && blockIdx.x == 0) {
        int tot = 0;
        for (int b = 0; b < B; ++b) tot += n_pos[b];
        float np = (float)tot;
        float loc = *loc_sum / (np * 4.0f);
        float conf = (*hard_sum + *pos_conf) / np;
        out[0] = 0.5f * loc + conf;
    }
}

extern "C" void kernel_launch(void* const* d_in, const int* in_sizes, int n_in,
                              void* d_out, int out_size, void* d_ws, size_t ws_size,
                              hipStream_t stream) {
    const float* locs_pred = (const float*)d_in[0];
    const float* cls_pred  = (const float*)d_in[1];
    const float* boxes     = (const float*)d_in[2];
    const int*   labels    = (const int*)d_in[3];
    const float* dboxes    = (const float*)d_in[4];

    int N = in_sizes[4] / 4;
    int B = in_sizes[0] / (4 * N);
    int O = in_sizes[3] / B;
    int BO = B * O;

    size_t BN = (size_t)B * N;
    char* ws = (char*)d_ws;
    int*   n_pos    = (int*)ws;                        // B ints
    float* loc_sum  = (float*)(ws + 128);
    float* pos_conf = (float*)(ws + 132);
    float* hard_sum = (float*)(ws + 136);
    float* vneg     = (float*)(ws + 256);              // BN f32
    int*   defbox_object = (int*)(ws + 256 + BN * 4);  // BO i32
    float* part_iou = (float*)(ws + 256 + BN * 4 + (size_t)BO * 4);
    int*   part_idx = (int*)(part_iou + (size_t)BO * CHUNKS);

    hipMemsetAsync(ws, 0, 256, stream);

    dim3 gop(BO, CHUNKS);
    k_obj_part<<<gop, 256, 0, stream>>>(boxes, dboxes, part_iou, part_idx, N, O);
    k_obj_reduce<<<(BO + 255) / 256, 256, 0, stream>>>(part_iou, part_idx,
                                                       defbox_object, BO);
    int tilesPerBatch = (N + TILEA - 1) / TILEA;            // 384
    int bpb = (tilesPerBatch + TPB - 1) / TPB;              // 24
    long long maxF4 = (((long long)B * N * CCLS) >> 2) - 1;
    dim3 gc(B * bpb);                                       // 768 blocks, 3/CU
    if (O == 16)
        k_conf<16><<<gc, 256, 0, stream>>>(locs_pred, cls_pred, boxes, labels, dboxes,
                                           defbox_object, vneg, n_pos, loc_sum,
                                           pos_conf, N, O, bpb, tilesPerBatch, maxF4);
    else
        k_conf<0><<<gc, 256, 0, stream>>>(locs_pred, cls_pred, boxes, labels, dboxes,
                                          defbox_object, vneg, n_pos, loc_sum,
                                          pos_conf, N, O, bpb, tilesPerBatch, maxF4);
    k_select<<<B, 1024, 0, stream>>>(vneg, n_pos, hard_sum, B, N);
    k_final<<<1, 1, 0, stream>>>(n_pos, loc_sum, pos_conf, hard_sum, (float*)d_out, B);
}

// Round 18
// 120.640 us; speedup vs baseline: 1.0799x; 1.0799x over previous
//
#include <hip/hip_runtime.h>
#include <math.h>

#define THRESH    0.5f
#define NEG_POSK  3
#define EPSf      1e-6f
#define CCLS      81
#define TILEA     64
#define CHUNKS    16
#define TPB       16      // tiles per block; 384/16 = 24 blocks/batch, all full

__device__ __forceinline__ float iou_xy(float ax0, float ay0, float ax1, float ay1,
                                        float bx0, float by0, float bx1, float by1) {
    float lx = fmaxf(ax0, bx0), ly = fmaxf(ay0, by0);
    float rx = fminf(ax1, bx1), ry = fminf(ay1, by1);
    float w = fmaxf(rx - lx, 0.f), h = fmaxf(ry - ly, 0.f);
    float inter = w * h;
    float aa = (ax1 - ax0) * (ay1 - ay0);
    float ab = (bx1 - bx0) * (by1 - by0);
    return inter / (aa + ab - inter);
}

__device__ __forceinline__ void gload16(const void* g, void* l) {
    __builtin_amdgcn_global_load_lds(
        (const __attribute__((address_space(1))) void*)g,
        (__attribute__((address_space(3))) void*)l, 16, 0, 0);
}

// ---------- kernel 1: per-object best anchor, single kernel via packed atomicMax -
// key = iou_bits<<32 | ~idx : non-negative floats are bit-monotone; for equal iou
// the max of ~idx selects the SMALLEST idx (JAX argmax first-max semantics).
__global__ __launch_bounds__(256) void k_obj(const float* __restrict__ boxes,
                                             const float* __restrict__ dboxes,
                                             unsigned long long* __restrict__ obj_key,
                                             int N, int O) {
    int bo = blockIdx.x;
    int c  = blockIdx.y;
    const float* bb = boxes + (size_t)bo * 4;
    float ax0 = bb[0], ay0 = bb[1], ax1 = bb[2], ay1 = bb[3];
    int chunk = (N + CHUNKS - 1) / CHUNKS;
    int n0 = c * chunk;
    int n1 = min(n0 + chunk, N);
    float best = -1.f; int bi = 0x7FFFFFFF;
    for (int n = n0 + threadIdx.x; n < n1; n += 256) {
        float4 d = ((const float4*)dboxes)[n];
        float dx0 = d.x - d.z * 0.5f, dy0 = d.y - d.w * 0.5f;
        float dx1 = d.x + d.z * 0.5f, dy1 = d.y + d.w * 0.5f;
        float iou = iou_xy(ax0, ay0, ax1, ay1, dx0, dy0, dx1, dy1);
        if (iou > best) { best = iou; bi = n; }   // ascending n + strict > = first max
    }
    #pragma unroll
    for (int dd = 1; dd < 64; dd <<= 1) {
        float v2 = __shfl_xor(best, dd); int i2 = __shfl_xor(bi, dd);
        if (v2 > best || (v2 == best && i2 < bi)) { best = v2; bi = i2; }
    }
    __shared__ float sv[4]; __shared__ int si[4];
    int w = threadIdx.x >> 6;
    if ((threadIdx.x & 63) == 0) { sv[w] = best; si[w] = bi; }
    __syncthreads();
    if (threadIdx.x == 0) {
        #pragma unroll
        for (int i = 1; i < 4; ++i)
            if (sv[i] > best || (sv[i] == best && si[i] < bi)) { best = sv[i]; bi = si[i]; }
        unsigned long long key = ((unsigned long long)__float_as_uint(best) << 32)
                               | (unsigned long long)(0xFFFFFFFFu - (unsigned)bi);
        atomicMax(&obj_key[bo], key);
    }
}

// ---------- kernel 2: per-wave pipelines (R13/R16 proven structure) --------------
// 4-wave blocks, 3/CU, per-wave 2-deep counted-vmcnt, no in-loop barriers,
// match distributed 4 lanes/anchor + division-free IoU, exp with 4 indep chains.
template<int OT>
__global__ __launch_bounds__(256)
void k_conf(const float* __restrict__ locs_pred,
            const float* __restrict__ cls,
            const float* __restrict__ boxes,
            const int* __restrict__ labels,
            const float* __restrict__ dboxes,
            const unsigned long long* __restrict__ obj_key,
            float* __restrict__ vneg,
            int* __restrict__ n_pos,
            float* __restrict__ loc_sum,
            float* __restrict__ pos_conf,
            int N, int O_rt, int bpb, int tilesPerBatch, long long maxF4) {
    const int O = OT ? OT : O_rt;
    __shared__ __align__(16) float sm[4][2][16 * CCLS];   // per-wave dbuf, 41.5 KB
    __shared__ float sbb[64];
    __shared__ int slab[16], sdbo[16];
    __shared__ float swl[4], swp[4];
    __shared__ int swc[4];
    const int tid = threadIdx.x;
    const int b  = blockIdx.x / bpb;
    const int t0 = (blockIdx.x % bpb) * TPB;
    const int tEnd = min(t0 + TPB, tilesPerBatch);

    if (tid < O * 4) sbb[tid] = boxes[(size_t)b * O * 4 + tid];
    else if (tid < O * 5) slab[tid - O * 4] = labels[(size_t)b * O + tid - O * 4];
    else if (tid < O * 6) {
        unsigned long long key = obj_key[(size_t)b * O + tid - O * 5];
        sdbo[tid - O * 5] = (int)(0xFFFFFFFFu - (unsigned)(key & 0xFFFFFFFFull));
    }

    const int lane = tid & 63, w = tid >> 6;
    const int j = lane & 15, q = lane >> 4;

    auto stage = [&](int buf, int t) {
        long long base4 = (((long long)b * N + (long long)t * TILEA + w * 16)
                           * CCLS) >> 2;               // exact (divisible by 4)
        const float4* g4 = (const float4*)cls;
        float4* s4 = (float4*)&sm[w][buf][0];
        #pragma unroll
        for (int k2 = 0; k2 < 5; ++k2) {
            long long gi = base4 + k2 * 64 + lane;
            if (gi > maxF4) gi = maxF4;                // clamp (tail-of-buffer OOB)
            gload16(g4 + gi, s4 + k2 * 64);            // wave-uniform LDS base
        }
        if (lane < 4) {
            long long gi = base4 + 320 + lane;
            if (gi > maxF4) gi = maxF4;
            gload16(g4 + gi, s4 + 320);                // tail 4 float4
        }
    };

    stage(0, t0);
    __syncthreads();

    float obx0[4], oby0[4], obx1[4], oby1[4], oarea[4];
    int odbo[4];
    #pragma unroll
    for (int oo = 0; oo < 4; ++oo) {
        int o = q * 4 + oo;
        obx0[oo] = sbb[o*4];   oby0[oo] = sbb[o*4+1];
        obx1[oo] = sbb[o*4+2]; oby1[oo] = sbb[o*4+3];
        oarea[oo] = (obx1[oo] - obx0[oo]) * (oby1[oo] - oby0[oo]);
        odbo[oo] = sdbo[o];
    }

    float pc = 0.f, ls = 0.f; int cnt = 0;

    auto phase2 = [&](int buf, int t) {
        int a0 = t * TILEA;
        int valid = min(TILEA, N - a0);
        int a = w * 16 + j;
        bool act = a < valid;
        int n = a0 + a;
        int nc = min(n, N - 1);
        float4 d = ((const float4*)dboxes)[nc];        // VMEM #1 (uncond)
        float dx0 = d.x - d.z * 0.5f, dy0 = d.y - d.w * 0.5f;
        float dx1 = d.x + d.z * 0.5f, dy1 = d.y + d.w * 0.5f;
        float areaD = d.z * d.w;
        float bi = -1.f, bu = 1.f; int bsel = q * 4;
        int fs = -1;
        #pragma unroll
        for (int oo = 0; oo < 4; ++oo) {
            float lx = fmaxf(obx0[oo], dx0), ly = fmaxf(oby0[oo], dy0);
            float rx = fminf(obx1[oo], dx1), ry = fminf(oby1[oo], dy1);
            float ww = fmaxf(rx - lx, 0.f), hh = fmaxf(ry - ly, 0.f);
            float inter = ww * hh;
            float uni = oarea[oo] + areaD - inter;
            float c1 = inter * bu, c2 = bi * uni;
            if (c1 > c2) { bi = inter; bu = uni; bsel = q * 4 + oo; }
            if (odbo[oo] == n) fs = q * 4 + oo;
        }
        #pragma unroll
        for (int dd = 16; dd < 64; dd <<= 1) {
            float oi = __shfl_xor(bi, dd), ou = __shfl_xor(bu, dd);
            int os = __shfl_xor(bsel, dd);
            int of = __shfl_xor(fs, dd);
            float c1 = oi * bu, c2 = bi * ou;
            if (c1 > c2 || (c1 == c2 && os < bsel)) { bi = oi; bu = ou; bsel = os; }
            fs = max(fs, of);
        }
        const float* row = &sm[w][buf][j * CCLS];
        float s_ = 0.f;
        if (act) {
            int c0 = q * 20;
            float e0 = 0.f, e1 = 0.f, e2 = 0.f, e3 = 0.f;   // 4 indep chains
            #pragma unroll
            for (int i = 0; i < 20; i += 4) {
                e0 += __expf(row[c0 + i]);
                e1 += __expf(row[c0 + i + 1]);
                e2 += __expf(row[c0 + i + 2]);
                e3 += __expf(row[c0 + i + 3]);
            }
            s_ = (e0 + e1) + (e2 + e3);
            if (q == 3) s_ += __expf(row[80]);
        }
        s_ += __shfl_xor(s_, 16);
        s_ += __shfl_xor(s_, 32);
        if (act && q == 0) {
            bool forced = fs >= 0;
            int sel = forced ? fs : bsel;
            bool meets = forced || (bi >= 0.5f * bu);
            int lbl = meets ? slab[sel] : 0;
            float conf = __logf(s_) - row[lbl];
            bool pos = (lbl != 0);
            size_t idx = (size_t)b * N + n;
            float4 p = ((const float4*)locs_pred)[idx];   // VMEM #2
            vneg[idx] = pos ? 0.f : conf;                 // VMEM #3
            if (pos) {
                pc += conf; cnt++;
                float bx0 = sbb[sel*4], by0 = sbb[sel*4+1];
                float bx1 = sbb[sel*4+2], by1 = sbb[sel*4+3];
                float bcx = (bx0 + bx1) * 0.5f, bcy = (by0 + by1) * 0.5f;
                float bw = bx1 - bx0, bh = by1 - by0;
                float t0f = (bcx - d.x) / (d.z / 10.0f + EPSf);
                float t1f = (bcy - d.y) / (d.w / 10.0f + EPSf);
                float t2f = __logf(bw / d.z + EPSf) * 5.0f;
                float t3f = __logf(bh / d.w + EPSf) * 5.0f;
                float dd;
                dd = fabsf(p.x - t0f); ls += (dd < 1.f) ? 0.5f*dd*dd : dd - 0.5f;
                dd = fabsf(p.y - t1f); ls += (dd < 1.f) ? 0.5f*dd*dd : dd - 0.5f;
                dd = fabsf(p.z - t2f); ls += (dd < 1.f) ? 0.5f*dd*dd : dd - 0.5f;
                dd = fabsf(p.w - t3f); ls += (dd < 1.f) ? 0.5f*dd*dd : dd - 0.5f;
            }
        }
    };

    int cur = 0;
    for (int t = t0; t < tEnd; ++t) {
        bool has_next = (t + 1 < tEnd);
        if (has_next) stage(cur ^ 1, t + 1);
        if (t == t0)
            asm volatile("s_waitcnt vmcnt(6)" ::: "memory");
        else if (has_next)
            asm volatile("s_waitcnt vmcnt(9)" ::: "memory");
        else
            asm volatile("s_waitcnt vmcnt(3)" ::: "memory");
        phase2(cur, t);
        cur ^= 1;
    }

    #pragma unroll
    for (int dd = 1; dd < 64; dd <<= 1) {
        pc  += __shfl_xor(pc, dd);
        ls  += __shfl_xor(ls, dd);
        cnt += __shfl_xor(cnt, dd);
    }
    if (lane == 0) { swp[w] = pc; swl[w] = ls; swc[w] = cnt; }
    __syncthreads();
    if (tid == 0) {
        float P = swp[0] + swp[1] + swp[2] + swp[3];
        float L = swl[0] + swl[1] + swl[2] + swl[3];
        int   C = swc[0] + swc[1] + swc[2] + swc[3];
        if (C) {
            atomicAdd(&n_pos[b], C);
            atomicAdd(loc_sum, L);
            atomicAdd(pos_conf, P);
        }
    }
}

// ---------- kernel 3: exact top-k sum (plain-LDS-atomic, proven fast) ------------
__device__ void wave_select(const int* hist, int nbins, int k, int* out_bin, int* out_k) {
    int lane = threadIdx.x & 63;
    int cum = 0;
    for (int c = nbins / 64 - 1; c >= 0; --c) {
        int val = hist[c * 64 + lane];
        int s = val;                           // descending suffix-sum within chunk
        for (int d = 1; d < 64; d <<= 1) {
            int t = __shfl_down(s, d);
            if (lane + d < 64) s += t;
        }
        int total = __shfl(s, 0);
        if (cum + total >= k) {
            unsigned long long mask = __ballot(cum + s >= k);
            int bl = 63 - __builtin_clzll(mask);
            int sB = __shfl(s, bl);
            int vB = __shfl(val, bl);
            if (lane == 0) {
                *out_bin = c * 64 + bl;
                *out_k = k - (cum + sB - vB);
            }
            return;
        }
        cum += total;
    }
    if (lane == 0) { *out_bin = 0; *out_k = 1; }
}

__global__ __launch_bounds__(1024) void k_select(const float* __restrict__ vneg,
                                                 const int* __restrict__ n_pos,
                                                 float* __restrict__ hard_sum,
                                                 int B, int N) {
    int b = blockIdx.x;
    const float* v = vneg + (size_t)b * N;
    __shared__ int hist[2048];
    __shared__ int bcast_bin, bcast_k;
    __shared__ float swv[16];
    __shared__ int swc[16];
    int np = n_pos[b];
    long long kk = (long long)NEG_POSK * np;
    if (kk > N) kk = N;
    int k = (int)kk;
    if (k <= 0) return;   // uniform across block
    int tid = threadIdx.x;

    for (int i = tid; i < 2048; i += 1024) hist[i] = 0;
    __syncthreads();
    for (int n = tid; n < N; n += 1024) {
        unsigned u = __float_as_uint(v[n]);
        atomicAdd(&hist[u >> 20], 1);
    }
    __syncthreads();
    if (tid < 64) wave_select(hist, 2048, k, &bcast_bin, &bcast_k);
    __syncthreads();
    int B1 = bcast_bin, k2 = bcast_k;

    for (int i = tid; i < 2048; i += 1024) hist[i] = 0;
    __syncthreads();
    for (int n = tid; n < N; n += 1024) {
        unsigned u = __float_as_uint(v[n]);
        if ((int)(u >> 20) == B1) atomicAdd(&hist[(u >> 9) & 0x7FF], 1);
    }
    __syncthreads();
    if (tid < 64) wave_select(hist, 2048, k2, &bcast_bin, &bcast_k);
    __syncthreads();
    int B2 = bcast_bin, k3 = bcast_k;
    unsigned pre = ((unsigned)B1 << 11) | (unsigned)B2;

    for (int i = tid; i < 512; i += 1024) hist[i] = 0;
    __syncthreads();
    for (int n = tid; n < N; n += 1024) {
        unsigned u = __float_as_uint(v[n]);
        if ((u >> 9) == pre) atomicAdd(&hist[u & 0x1FF], 1);
    }
    __syncthreads();
    if (tid < 64) wave_select(hist, 512, k3, &bcast_bin, &bcast_k);
    __syncthreads();
    unsigned tau_bits = (pre << 9) | (unsigned)bcast_bin;
    float tau = __uint_as_float(tau_bits);

    float ssum = 0.f; int scnt = 0;
    for (int n = tid; n < N; n += 1024) {
        float x = v[n];
        if (x > tau) { ssum += x; scnt++; }
    }
    for (int d = 1; d < 64; d <<= 1) {
        ssum += __shfl_xor(ssum, d);
        scnt += __shfl_xor(scnt, d);
    }
    int w = tid >> 6;
    if ((tid & 63) == 0) { swv[w] = ssum; swc[w] = scnt; }
    __syncthreads();
    if (tid == 0) {
        float S = 0.f; int Ct = 0;
        for (int i = 0; i < 16; ++i) { S += swv[i]; Ct += swc[i]; }
        float hb = S + (float)(k - Ct) * tau;
        atomicAdd(hard_sum, hb);
    }
}

// ---------- kernel 4: finalize ---------------------------------------------------
__global__ void k_final(const int* __restrict__ n_pos,
                        const float* __restrict__ loc_sum,
                        const float* __restrict__ pos_conf,
                        const float* __restrict__ hard_sum,
                        float* __restrict__ out, int B) {
    if (threadIdx.x == 0 && blockIdx.x == 0) {
        int tot = 0;
        for (int b = 0; b < B; ++b) tot += n_pos[b];
        float np = (float)tot;
        float loc = *loc_sum / (np * 4.0f);
        float conf = (*hard_sum + *pos_conf) / np;
        out[0] = 0.5f * loc + conf;
    }
}

extern "C" void kernel_launch(void* const* d_in, const int* in_sizes, int n_in,
                              void* d_out, int out_size, void* d_ws, size_t ws_size,
                              hipStream_t stream) {
    const float* locs_pred = (const float*)d_in[0];
    const float* cls_pred  = (const float*)d_in[1];
    const float* boxes     = (const float*)d_in[2];
    const int*   labels    = (const int*)d_in[3];
    const float* dboxes    = (const float*)d_in[4];

    int N = in_sizes[4] / 4;
    int B = in_sizes[0] / (4 * N);
    int O = in_sizes[3] / B;
    int BO = B * O;

    size_t BN = (size_t)B * N;
    char* ws = (char*)d_ws;
    int*   n_pos    = (int*)ws;                        // B ints
    float* loc_sum  = (float*)(ws + 128);
    float* pos_conf = (float*)(ws + 132);
    float* hard_sum = (float*)(ws + 136);
    unsigned long long* obj_key = (unsigned long long*)(ws + 256);   // BO u64 (zeroed)
    float* vneg     = (float*)(ws + 256 + (size_t)BO * 8);           // BN f32

    hipMemsetAsync(ws, 0, 256 + (size_t)BO * 8, stream);   // scalars + obj_key

    dim3 gop(BO, CHUNKS);
    k_obj<<<gop, 256, 0, stream>>>(boxes, dboxes, obj_key, N, O);
    int tilesPerBatch = (N + TILEA - 1) / TILEA;            // 384
    int bpb = (tilesPerBatch + TPB - 1) / TPB;              // 24
    long long maxF4 = (((long long)B * N * CCLS) >> 2) - 1;
    dim3 gc(B * bpb);                                       // 768 blocks, 3/CU
    if (O == 16)
        k_conf<16><<<gc, 256, 0, stream>>>(locs_pred, cls_pred, boxes, labels, dboxes,
                                           obj_key, vneg, n_pos, loc_sum,
                                           pos_conf, N, O, bpb, tilesPerBatch, maxF4);
    else
        k_conf<0><<<gc, 256, 0, stream>>>(locs_pred, cls_pred, boxes, labels, dboxes,
                                          obj_key, vneg, n_pos, loc_sum,
                                          pos_conf, N, O, bpb, tilesPerBatch, maxF4);
    k_select<<<B, 1024, 0, stream>>>(vneg, n_pos, hard_sum, B, N);
    k_final<<<1, 1, 0, stream>>>(n_pos, loc_sum, pos_conf, hard_sum, (float*)d_out, B);
}

// Round 20
// 120.063 us; speedup vs baseline: 1.0851x; 1.0048x over previous
//
#include <hip/hip_runtime.h>
#include <math.h>

#define THRESH    0.5f
#define NEG_POSK  3
#define EPSf      1e-6f
#define CCLS      81
#define TILEA     64
#define CHUNKS    16
#define TPB       16      // tiles per block; 384/16 = 24 blocks/batch, all full

__device__ __forceinline__ float iou_xy(float ax0, float ay0, float ax1, float ay1,
                                        float bx0, float by0, float bx1, float by1) {
    float lx = fmaxf(ax0, bx0), ly = fmaxf(ay0, by0);
    float rx = fminf(ax1, bx1), ry = fminf(ay1, by1);
    float w = fmaxf(rx - lx, 0.f), h = fmaxf(ry - ly, 0.f);
    float inter = w * h;
    float aa = (ax1 - ax0) * (ay1 - ay0);
    float ab = (bx1 - bx0) * (by1 - by0);
    return inter / (aa + ab - inter);
}

__device__ __forceinline__ void gload16(const void* g, void* l) {
    __builtin_amdgcn_global_load_lds(
        (const __attribute__((address_space(1))) void*)g,
        (__attribute__((address_space(3))) void*)l, 16, 0, 0);
}

// ---------- kernel 1: per-object best anchor, single kernel via packed atomicMax -
// key = iou_bits<<32 | ~idx : non-negative floats are bit-monotone; for equal iou
// the max of ~idx selects the SMALLEST idx (JAX argmax first-max semantics).
__global__ __launch_bounds__(256) void k_obj(const float* __restrict__ boxes,
                                             const float* __restrict__ dboxes,
                                             unsigned long long* __restrict__ obj_key,
                                             int N, int O) {
    int bo = blockIdx.x;
    int c  = blockIdx.y;
    const float* bb = boxes + (size_t)bo * 4;
    float ax0 = bb[0], ay0 = bb[1], ax1 = bb[2], ay1 = bb[3];
    int chunk = (N + CHUNKS - 1) / CHUNKS;
    int n0 = c * chunk;
    int n1 = min(n0 + chunk, N);
    float best = -1.f; int bi = 0x7FFFFFFF;
    for (int n = n0 + threadIdx.x; n < n1; n += 256) {
        float4 d = ((const float4*)dboxes)[n];
        float dx0 = d.x - d.z * 0.5f, dy0 = d.y - d.w * 0.5f;
        float dx1 = d.x + d.z * 0.5f, dy1 = d.y + d.w * 0.5f;
        float iou = iou_xy(ax0, ay0, ax1, ay1, dx0, dy0, dx1, dy1);
        if (iou > best) { best = iou; bi = n; }   // ascending n + strict > = first max
    }
    #pragma unroll
    for (int dd = 1; dd < 64; dd <<= 1) {
        float v2 = __shfl_xor(best, dd); int i2 = __shfl_xor(bi, dd);
        if (v2 > best || (v2 == best && i2 < bi)) { best = v2; bi = i2; }
    }
    __shared__ float sv[4]; __shared__ int si[4];
    int w = threadIdx.x >> 6;
    if ((threadIdx.x & 63) == 0) { sv[w] = best; si[w] = bi; }
    __syncthreads();
    if (threadIdx.x == 0) {
        #pragma unroll
        for (int i = 1; i < 4; ++i)
            if (sv[i] > best || (sv[i] == best && si[i] < bi)) { best = sv[i]; bi = si[i]; }
        unsigned long long key = ((unsigned long long)__float_as_uint(best) << 32)
                               | (unsigned long long)(0xFFFFFFFFu - (unsigned)bi);
        atomicMax(&obj_key[bo], key);
    }
}

// ---------- kernel 2: per-wave pipelines (R13/R16 proven structure) --------------
// 4-wave blocks, 3/CU, per-wave 2-deep counted-vmcnt, no in-loop barriers,
// match distributed 4 lanes/anchor + division-free IoU, exp with 4 indep chains.
template<int OT>
__global__ __launch_bounds__(256)
void k_conf(const float* __restrict__ locs_pred,
            const float* __restrict__ cls,
            const float* __restrict__ boxes,
            const int* __restrict__ labels,
            const float* __restrict__ dboxes,
            const unsigned long long* __restrict__ obj_key,
            float* __restrict__ vneg,
            int* __restrict__ n_pos,
            float* __restrict__ loc_sum,
            float* __restrict__ pos_conf,
            int N, int O_rt, int bpb, int tilesPerBatch, long long maxF4) {
    const int O = OT ? OT : O_rt;
    __shared__ __align__(16) float sm[4][2][16 * CCLS];   // per-wave dbuf, 41.5 KB
    __shared__ float sbb[64];
    __shared__ int slab[16], sdbo[16];
    __shared__ float swl[4], swp[4];
    __shared__ int swc[4];
    const int tid = threadIdx.x;
    const int b  = blockIdx.x / bpb;
    const int t0 = (blockIdx.x % bpb) * TPB;
    const int tEnd = min(t0 + TPB, tilesPerBatch);

    if (tid < O * 4) sbb[tid] = boxes[(size_t)b * O * 4 + tid];
    else if (tid < O * 5) slab[tid - O * 4] = labels[(size_t)b * O + tid - O * 4];
    else if (tid < O * 6) {
        unsigned long long key = obj_key[(size_t)b * O + tid - O * 5];
        sdbo[tid - O * 5] = (int)(0xFFFFFFFFu - (unsigned)(key & 0xFFFFFFFFull));
    }

    const int lane = tid & 63, w = tid >> 6;
    const int j = lane & 15, q = lane >> 4;

    auto stage = [&](int buf, int t) {
        long long base4 = (((long long)b * N + (long long)t * TILEA + w * 16)
                           * CCLS) >> 2;               // exact (divisible by 4)
        const float4* g4 = (const float4*)cls;
        float4* s4 = (float4*)&sm[w][buf][0];
        #pragma unroll
        for (int k2 = 0; k2 < 5; ++k2) {
            long long gi = base4 + k2 * 64 + lane;
            if (gi > maxF4) gi = maxF4;                // clamp (tail-of-buffer OOB)
            gload16(g4 + gi, s4 + k2 * 64);            // wave-uniform LDS base
        }
        if (lane < 4) {
            long long gi = base4 + 320 + lane;
            if (gi > maxF4) gi = maxF4;
            gload16(g4 + gi, s4 + 320);                // tail 4 float4
        }
    };

    stage(0, t0);
    __syncthreads();

    float obx0[4], oby0[4], obx1[4], oby1[4], oarea[4];
    int odbo[4];
    #pragma unroll
    for (int oo = 0; oo < 4; ++oo) {
        int o = q * 4 + oo;
        obx0[oo] = sbb[o*4];   oby0[oo] = sbb[o*4+1];
        obx1[oo] = sbb[o*4+2]; oby1[oo] = sbb[o*4+3];
        oarea[oo] = (obx1[oo] - obx0[oo]) * (oby1[oo] - oby0[oo]);
        odbo[oo] = sdbo[o];
    }

    float pc = 0.f, ls = 0.f; int cnt = 0;

    auto phase2 = [&](int buf, int t) {
        int a0 = t * TILEA;
        int valid = min(TILEA, N - a0);
        int a = w * 16 + j;
        bool act = a < valid;
        int n = a0 + a;
        int nc = min(n, N - 1);
        float4 d = ((const float4*)dboxes)[nc];        // VMEM #1 (uncond)
        float dx0 = d.x - d.z * 0.5f, dy0 = d.y - d.w * 0.5f;
        float dx1 = d.x + d.z * 0.5f, dy1 = d.y + d.w * 0.5f;
        float areaD = d.z * d.w;
        float bi = -1.f, bu = 1.f; int bsel = q * 4;
        int fs = -1;
        #pragma unroll
        for (int oo = 0; oo < 4; ++oo) {
            float lx = fmaxf(obx0[oo], dx0), ly = fmaxf(oby0[oo], dy0);
            float rx = fminf(obx1[oo], dx1), ry = fminf(oby1[oo], dy1);
            float ww = fmaxf(rx - lx, 0.f), hh = fmaxf(ry - ly, 0.f);
            float inter = ww * hh;
            float uni = oarea[oo] + areaD - inter;
            float c1 = inter * bu, c2 = bi * uni;
            if (c1 > c2) { bi = inter; bu = uni; bsel = q * 4 + oo; }
            if (odbo[oo] == n) fs = q * 4 + oo;
        }
        #pragma unroll
        for (int dd = 16; dd < 64; dd <<= 1) {
            float oi = __shfl_xor(bi, dd), ou = __shfl_xor(bu, dd);
            int os = __shfl_xor(bsel, dd);
            int of = __shfl_xor(fs, dd);
            float c1 = oi * bu, c2 = bi * ou;
            if (c1 > c2 || (c1 == c2 && os < bsel)) { bi = oi; bu = ou; bsel = os; }
            fs = max(fs, of);
        }
        const float* row = &sm[w][buf][j * CCLS];
        float s_ = 0.f;
        if (act) {
            int c0 = q * 20;
            float e0 = 0.f, e1 = 0.f, e2 = 0.f, e3 = 0.f;   // 4 indep chains
            #pragma unroll
            for (int i = 0; i < 20; i += 4) {
                e0 += __expf(row[c0 + i]);
                e1 += __expf(row[c0 + i + 1]);
                e2 += __expf(row[c0 + i + 2]);
                e3 += __expf(row[c0 + i + 3]);
            }
            s_ = (e0 + e1) + (e2 + e3);
            if (q == 3) s_ += __expf(row[80]);
        }
        s_ += __shfl_xor(s_, 16);
        s_ += __shfl_xor(s_, 32);
        if (act && q == 0) {
            bool forced = fs >= 0;
            int sel = forced ? fs : bsel;
            bool meets = forced || (bi >= 0.5f * bu);
            int lbl = meets ? slab[sel] : 0;
            float conf = __logf(s_) - row[lbl];
            bool pos = (lbl != 0);
            size_t idx = (size_t)b * N + n;
            float4 p = ((const float4*)locs_pred)[idx];   // VMEM #2
            vneg[idx] = pos ? 0.f : conf;                 // VMEM #3
            if (pos) {
                pc += conf; cnt++;
                float bx0 = sbb[sel*4], by0 = sbb[sel*4+1];
                float bx1 = sbb[sel*4+2], by1 = sbb[sel*4+3];
                float bcx = (bx0 + bx1) * 0.5f, bcy = (by0 + by1) * 0.5f;
                float bw = bx1 - bx0, bh = by1 - by0;
                float t0f = (bcx - d.x) / (d.z / 10.0f + EPSf);
                float t1f = (bcy - d.y) / (d.w / 10.0f + EPSf);
                float t2f = __logf(bw / d.z + EPSf) * 5.0f;
                float t3f = __logf(bh / d.w + EPSf) * 5.0f;
                float dd;
                dd = fabsf(p.x - t0f); ls += (dd < 1.f) ? 0.5f*dd*dd : dd - 0.5f;
                dd = fabsf(p.y - t1f); ls += (dd < 1.f) ? 0.5f*dd*dd : dd - 0.5f;
                dd = fabsf(p.z - t2f); ls += (dd < 1.f) ? 0.5f*dd*dd : dd - 0.5f;
                dd = fabsf(p.w - t3f); ls += (dd < 1.f) ? 0.5f*dd*dd : dd - 0.5f;
            }
        }
    };

    int cur = 0;
    for (int t = t0; t < tEnd; ++t) {
        bool has_next = (t + 1 < tEnd);
        if (has_next) stage(cur ^ 1, t + 1);
        if (t == t0)
            asm volatile("s_waitcnt vmcnt(6)" ::: "memory");
        else if (has_next)
            asm volatile("s_waitcnt vmcnt(9)" ::: "memory");
        else
            asm volatile("s_waitcnt vmcnt(3)" ::: "memory");
        phase2(cur, t);
        cur ^= 1;
    }

    #pragma unroll
    for (int dd = 1; dd < 64; dd <<= 1) {
        pc  += __shfl_xor(pc, dd);
        ls  += __shfl_xor(ls, dd);
        cnt += __shfl_xor(cnt, dd);
    }
    if (lane == 0) { swp[w] = pc; swl[w] = ls; swc[w] = cnt; }
    __syncthreads();
    if (tid == 0) {
        float P = swp[0] + swp[1] + swp[2] + swp[3];
        float L = swl[0] + swl[1] + swl[2] + swl[3];
        int   C = swc[0] + swc[1] + swc[2] + swc[3];
        if (C) {
            atomicAdd(&n_pos[b], C);
            atomicAdd(loc_sum, L);
            atomicAdd(pos_conf, P);
        }
    }
}

// ---------- kernel 3: exact top-k sum (plain-LDS-atomic, proven fast) ------------
__device__ void wave_select(const int* hist, int nbins, int k, int* out_bin, int* out_k) {
    int lane = threadIdx.x & 63;
    int cum = 0;
    for (int c = nbins / 64 - 1; c >= 0; --c) {
        int val = hist[c * 64 + lane];
        int s = val;                           // descending suffix-sum within chunk
        for (int d = 1; d < 64; d <<= 1) {
            int t = __shfl_down(s, d);
            if (lane + d < 64) s += t;
        }
        int total = __shfl(s, 0);
        if (cum + total >= k) {
            unsigned long long mask = __ballot(cum + s >= k);
            int bl = 63 - __builtin_clzll(mask);
            int sB = __shfl(s, bl);
            int vB = __shfl(val, bl);
            if (lane == 0) {
                *out_bin = c * 64 + bl;
                *out_k = k - (cum + sB - vB);
            }
            return;
        }
        cum += total;
    }
    if (lane == 0) { *out_bin = 0; *out_k = 1; }
}

__global__ __launch_bounds__(1024) void k_select(const float* __restrict__ vneg,
                                                 const int* __restrict__ n_pos,
                                                 float* __restrict__ hard_sum,
                                                 int B, int N) {
    int b = blockIdx.x;
    const float* v = vneg + (size_t)b * N;
    __shared__ int hist[2048];
    __shared__ int bcast_bin, bcast_k;
    __shared__ float swv[16];
    __shared__ int swc[16];
    int np = n_pos[b];
    long long kk = (long long)NEG_POSK * np;
    if (kk > N) kk = N;
    int k = (int)kk;
    if (k <= 0) return;   // uniform across block
    int tid = threadIdx.x;

    for (int i = tid; i < 2048; i += 1024) hist[i] = 0;
    __syncthreads();
    for (int n = tid; n < N; n += 1024) {
        unsigned u = __float_as_uint(v[n]);
        atomicAdd(&hist[u >> 20], 1);
    }
    __syncthreads();
    if (tid < 64) wave_select(hist, 2048, k, &bcast_bin, &bcast_k);
    __syncthreads();
    int B1 = bcast_bin, k2 = bcast_k;

    for (int i = tid; i < 2048; i += 1024) hist[i] = 0;
    __syncthreads();
    for (int n = tid; n < N; n += 1024) {
        unsigned u = __float_as_uint(v[n]);
        if ((int)(u >> 20) == B1) atomicAdd(&hist[(u >> 9) & 0x7FF], 1);
    }
    __syncthreads();
    if (tid < 64) wave_select(hist, 2048, k2, &bcast_bin, &bcast_k);
    __syncthreads();
    int B2 = bcast_bin, k3 = bcast_k;
    unsigned pre = ((unsigned)B1 << 11) | (unsigned)B2;

    for (int i = tid; i < 512; i += 1024) hist[i] = 0;
    __syncthreads();
    for (int n = tid; n < N; n += 1024) {
        unsigned u = __float_as_uint(v[n]);
        if ((u >> 9) == pre) atomicAdd(&hist[u & 0x1FF], 1);
    }
    __syncthreads();
    if (tid < 64) wave_select(hist, 512, k3, &bcast_bin, &bcast_k);
    __syncthreads();
    unsigned tau_bits = (pre << 9) | (unsigned)bcast_bin;
    float tau = __uint_as_float(tau_bits);

    float ssum = 0.f; int scnt = 0;
    for (int n = tid; n < N; n += 1024) {
        float x = v[n];
        if (x > tau) { ssum += x; scnt++; }
    }
    for (int d = 1; d < 64; d <<= 1) {
        ssum += __shfl_xor(ssum, d);
        scnt += __shfl_xor(scnt, d);
    }
    int w = tid >> 6;
    if ((tid & 63) == 0) { swv[w] = ssum; swc[w] = scnt; }
    __syncthreads();
    if (tid == 0) {
        float S = 0.f; int Ct = 0;
        for (int i = 0; i < 16; ++i) { S += swv[i]; Ct += swc[i]; }
        float hb = S + (float)(k - Ct) * tau;
        atomicAdd(hard_sum, hb);
    }
}

// ---------- kernel 4: finalize ---------------------------------------------------
__global__ void k_final(const int* __restrict__ n_pos,
                        const float* __restrict__ loc_sum,
                        const float* __restrict__ pos_conf,
                        const float* __restrict__ hard_sum,
                        float* __restrict__ out, int B) {
    if (threadIdx.x == 0 && blockIdx.x == 0) {
        int tot = 0;
        for (int b = 0; b < B; ++b) tot += n_pos[b];
        float np = (float)tot;
        float loc = *loc_sum / (np * 4.0f);
        float conf = (*hard_sum + *pos_conf) / np;
        out[0] = 0.5f * loc + conf;
    }
}

extern "C" void kernel_launch(void* const* d_in, const int* in_sizes, int n_in,
                              void* d_out, int out_size, void* d_ws, size_t ws_size,
                              hipStream_t stream) {
    const float* locs_pred = (const float*)d_in[0];
    const float* cls_pred  = (const float*)d_in[1];
    const float* boxes     = (const float*)d_in[2];
    const int*   labels    = (const int*)d_in[3];
    const float* dboxes    = (const float*)d_in[4];

    int N = in_sizes[4] / 4;
    int B = in_sizes[0] / (4 * N);
    int O = in_sizes[3] / B;
    int BO = B * O;

    size_t BN = (size_t)B * N;
    char* ws = (char*)d_ws;
    int*   n_pos    = (int*)ws;                        // B ints
    float* loc_sum  = (float*)(ws + 128);
    float* pos_conf = (float*)(ws + 132);
    float* hard_sum = (float*)(ws + 136);
    unsigned long long* obj_key = (unsigned long long*)(ws + 256);   // BO u64 (zeroed)
    float* vneg     = (float*)(ws + 256 + (size_t)BO * 8);           // BN f32

    hipMemsetAsync(ws, 0, 256 + (size_t)BO * 8, stream);   // scalars + obj_key

    dim3 gop(BO, CHUNKS);
    k_obj<<<gop, 256, 0, stream>>>(boxes, dboxes, obj_key, N, O);
    int tilesPerBatch = (N + TILEA - 1) / TILEA;            // 384
    int bpb = (tilesPerBatch + TPB - 1) / TPB;              // 24
    long long maxF4 = (((long long)B * N * CCLS) >> 2) - 1;
    dim3 gc(B * bpb);                                       // 768 blocks, 3/CU
    if (O == 16)
        k_conf<16><<<gc, 256, 0, stream>>>(locs_pred, cls_pred, boxes, labels, dboxes,
                                           obj_key, vneg, n_pos, loc_sum,
                                           pos_conf, N, O, bpb, tilesPerBatch, maxF4);
    else
        k_conf<0><<<gc, 256, 0, stream>>>(locs_pred, cls_pred, boxes, labels, dboxes,
                                          obj_key, vneg, n_pos, loc_sum,
                                          pos_conf, N, O, bpb, tilesPerBatch, maxF4);
    k_select<<<B, 1024, 0, stream>>>(vneg, n_pos, hard_sum, B, N);
    k_final<<<1, 1, 0, stream>>>(n_pos, loc_sum, pos_conf, hard_sum, (float*)d_out, B);
}